// Round 3
// baseline (238.961 us; speedup 1.0000x reference)
//
#include <hip/hip_runtime.h>
#include <hip/hip_cooperative_groups.h>

namespace cg = cooperative_groups;

#define F_ELEMS 2097152            // B*T*H*W = 4*8*256*256 (elements per field)
#define IMG 65536                  // H*W

typedef _Float16 half8  __attribute__((ext_vector_type(8)));
typedef _Float16 half2v __attribute__((ext_vector_type(2)));
typedef _Float16 half4v __attribute__((ext_vector_type(4)));
typedef float    floatx4 __attribute__((ext_vector_type(4)));

__device__ __forceinline__ float sigm(float x){ return 1.0f/(1.0f + __expf(-x)); }
__device__ __forceinline__ float tanh_fast(float x){
    float t = __expf(2.0f*x);
    return 1.0f - 2.0f/(t + 1.0f);
}

// ---------------------------------------------------------------------------
// Shared device bodies. Phase A: conv 3x3 (8ch -> 64ch) MFMA implicit GEMM,
// operand-swapped so lanes hold 4 consecutive pixels of one oc (half4 stores).
// Fields f16: 0 kappa^2, 1 m1, 2 m2, 3 Hxx, 4 Hs, 5 Hyy, 6 tau.
// Phase B: z = A(A(x)); out += 0.5*sum(D r^2) + sum(log tau).
// ---------------------------------------------------------------------------

__device__ __forceinline__ void conv_body(
    const float* __restrict__ x, const float* __restrict__ w,
    _Float16* __restrict__ fld, float* __restrict__ out,
    int strip, int b, int zero_flag,
    _Float16* xt /*[4*258*8]*/, _Float16* Wl /*[12*64*8]*/)
{
    const int tid = threadIdx.x;
    const int i0  = strip << 1;          // strip of 2 rows

    if (zero_flag && tid == 0) out[0] = 0.0f;

    // ---- stage x (f32 -> f16, channel pairs for 4B LDS writes) ----
    for (int e = tid; e < 258*4*4; e += 256){
        int cc = e % 258;
        int rr = (e/258) & 3;
        int cp = e / (258*4);            // channel pair 0..3
        int gi = i0 - 1 + rr, gj = cc - 1;
        float v0 = 0.0f, v1 = 0.0f;
        if (gi >= 0 && gi < 256 && gj >= 0 && gj < 256){
            int base = ((b*8 + 2*cp) << 16) + (gi << 8) + gj;
            v0 = x[base];
            v1 = x[base + IMG];
        }
        half2v h; h[0] = (_Float16)v0; h[1] = (_Float16)v1;
        *(half2v*)&xt[(rr*258 + cc)*8 + 2*cp] = h;
    }
    // ---- stage weights [tap][oc][c], zero-pad taps 9..11 ----
    for (int e = tid; e < 12*64*8; e += 256){
        int c  = e & 7;
        int oc = (e >> 3) & 63;
        int t  = e >> 9;
        float v = (t < 9) ? w[(oc*8 + c)*9 + t] : 0.0f;
        Wl[e] = (_Float16)v;             // e == (t*64+oc)*8 + c
    }
    __syncthreads();

    const int lane = tid & 63;
    const int quad = lane >> 4;
    const int l16  = lane & 15;
    const int wv   = tid >> 6;

    // Weight frags (B operand): B[k=quad*8+j][n=oc=ot*16+l16]
    half8 afr[4][3];
    int boff[3];
    #pragma unroll
    for (int s = 0; s < 3; ++s){
        int t  = s*4 + quad;
        afr[0][s] = *(const half8*)&Wl[(t*64 +  0 + l16)*8];
        afr[1][s] = *(const half8*)&Wl[(t*64 + 16 + l16)*8];
        afr[2][s] = *(const half8*)&Wl[(t*64 + 32 + l16)*8];
        afr[3][s] = *(const half8*)&Wl[(t*64 + 48 + l16)*8];
        int tc = (t < 9) ? t : 8;        // taps >=9 have zero weights
        int dh = tc / 3, dw = tc - dh*3;
        boff[s] = (dh*258 + dw)*8;
    }

    // it-invariant epilogue constants
    const bool lo  = (l16 < 8);
    const int  tlo = l16 << 16, thi = (l16 - 8) << 16;
    const int  off0 = lo ? (0*F_ELEMS + tlo) : (1*F_ELEMS + thi);  // kappa^2 / m1
    const int  off1 = lo ? (2*F_ELEMS + tlo) : (3*F_ELEMS + thi);  // m2 / Hxx
    const int  off2 = 4*F_ELEMS + tlo;                             // Hs (lo only)
    const int  off3 = lo ? (5*F_ELEMS + tlo) : (6*F_ELEMS + thi);  // Hyy / tau

    // 32 groups of 16 px (2 rows x 16 col-groups); 8 iters per wave
    #pragma unroll 2
    for (int it = 0; it < 8; ++it){
        const int g   = it*4 + wv;
        const int r   = g >> 4;
        const int jb  = ((g & 15) << 4) + l16;   // A-frag row = px = l16
        const int xoff = (r*258 + jb)*8;

        floatx4 acc0 = {0,0,0,0}, acc1 = {0,0,0,0}, acc2 = {0,0,0,0}, acc3 = {0,0,0,0};
        #pragma unroll
        for (int s = 0; s < 3; ++s){
            half8 bf = *(const half8*)&xt[xoff + boff[s]];
            acc0 = __builtin_amdgcn_mfma_f32_16x16x32_f16(bf, afr[0][s], acc0, 0, 0, 0);
            acc1 = __builtin_amdgcn_mfma_f32_16x16x32_f16(bf, afr[1][s], acc1, 0, 0, 0);
            acc2 = __builtin_amdgcn_mfma_f32_16x16x32_f16(bf, afr[2][s], acc2, 0, 0, 0);
            acc3 = __builtin_amdgcn_mfma_f32_16x16x32_f16(bf, afr[3][s], acc3, 0, 0, 0);
        }

        // epilogue: lane holds px = jb0 + quad*4 + rg of oc = ot*16+l16
        const int jb0  = (g & 15) << 4;
        const int pixb = (b << 19) + ((i0 + r) << 8) + jb0 + (quad << 2);

        half4v h0, h1, h2, h3;
        #pragma unroll
        for (int rg = 0; rg < 4; ++rg){
            float v0 = acc0[rg];
            float s0 = 0.99f*sigm(v0) + 0.01f;
            h0[rg] = (_Float16)(lo ? s0*s0 : v0);
            float v1 = acc1[rg];
            h1[rg] = (_Float16)(lo ? v1 : 0.99f*sigm(v1) + 0.01f);
            float th  = 0.1f*tanh_fast(acc2[rg]);
            float oth = __shfl_xor(th, 8, 64);
            h2[rg] = (_Float16)(th + oth);
            float sg = sigm(acc3[rg]);
            h3[rg] = (_Float16)(lo ? 0.99f*sg + 0.01f : 9.9f*sg + 0.1f);
        }
        *(half4v*)&fld[off0 + pixb] = h0;
        *(half4v*)&fld[off1 + pixb] = h1;
        if (lo) *(half4v*)&fld[off2 + pixb] = h2;
        *(half4v*)&fld[off3 + pixb] = h3;
    }
}

__device__ __forceinline__ void ldf4(const _Float16* __restrict__ p, float o[4]){
    half4v h = *(const half4v*)p;
    o[0] = (float)h[0]; o[1] = (float)h[1]; o[2] = (float)h[2]; o[3] = (float)h[3];
}

__device__ __forceinline__ void row6(const float* __restrict__ u, int rb, int j0, float v[6]){
    const float4 c4 = *(const float4*)&u[rb + j0];
    v[1] = c4.x; v[2] = c4.y; v[3] = c4.z; v[4] = c4.w;
    v[0] = (j0 > 0)   ? u[rb + j0 - 1] : 0.0f;
    v[5] = (j0 < 252) ? u[rb + j0 + 4] : 0.0f;
}

__device__ __forceinline__ void stencil4(const float k2[4], const float m1[4],
    const float m2[4], const float hx[4], const float hs[4], const float hy[4],
    const float vc[6], const float vn[6], const float vs[6], float rp[4])
{
    #pragma unroll
    for (int p = 0; p < 4; ++p){
        float hxx = hx[p], hyy = hy[p];
        rp[p] = (k2[p] + 2.0f*(hxx + hyy))*vc[p+1]
              + (0.5f*m1[p] - hxx)*vc[p+2]
              - (0.5f*m1[p] + hxx)*vc[p]
              + (0.5f*m2[p] - hyy)*vn[p+1]
              - (0.5f*m2[p] + hyy)*vs[p+1]
              - 0.25f*hs[p]*(vn[p+2] - vs[p+2] - vn[p] + vs[p]);
    }
}

#define YSW 268
__device__ __forceinline__ void fused_body(
    const float* __restrict__ x, const _Float16* __restrict__ fld,
    float* __restrict__ out, int istrip, int bt,
    float* ys /*[18*YSW]*/, float* redA /*[4]*/, float* redB /*[4]*/)
{
    const int tid = threadIdx.x;
    const int cg  = tid & 63;            // col group (4 cols)
    const int rw  = tid >> 6;            // row within pass
    const int jc  = cg << 2;
    const int t   = bt & 7;
    const int i0  = istrip << 4;

    // zero halo columns (j=-1 -> idx 3, j=256 -> idx 260)
    if (tid < 18){ ys[tid*YSW + 3] = 0.0f; ys[tid*YSW + 260] = 0.0f; }

    // ---- phase 1: y = A(x) on rows i0-1 .. i0+16 ----
    for (int p = 0; p < 5; ++p){
        int yr = p*4 + rw;               // wave-uniform branch
        if (yr < 18){
            int iy = i0 - 1 + yr;
            float y[4] = {0,0,0,0};
            if (iy >= 0 && iy < 256){
                int pix = (bt << 16) + (iy << 8) + jc;
                int rb  = pix - jc;
                float vc[6], vn[6], vs[6];
                row6(x, rb, jc, vc);
                if (iy < 255) row6(x, rb + 256, jc, vn);
                else { vn[0]=vn[1]=vn[2]=vn[3]=vn[4]=vn[5]=0.0f; }
                if (iy > 0) row6(x, rb - 256, jc, vs);
                else { vs[0]=vs[1]=vs[2]=vs[3]=vs[4]=vs[5]=0.0f; }
                float k2[4], m1[4], m2[4], hx[4], hs[4], hy[4];
                ldf4(&fld[0*F_ELEMS + pix], k2);
                ldf4(&fld[1*F_ELEMS + pix], m1);
                ldf4(&fld[2*F_ELEMS + pix], m2);
                ldf4(&fld[3*F_ELEMS + pix], hx);
                ldf4(&fld[4*F_ELEMS + pix], hs);
                ldf4(&fld[5*F_ELEMS + pix], hy);
                stencil4(k2, m1, m2, hx, hs, hy, vc, vn, vs, y);
            }
            float4 y4 = make_float4(y[0], y[1], y[2], y[3]);
            *(float4*)&ys[yr*YSW + 4 + jc] = y4;
        }
    }
    __syncthreads();

    // ---- phase 2: z = A(y); accumulate D*r^2 and prod(tau) ----
    float local = 0.0f;
    float lprod = 1.0f;                  // product of 16 taus, range safe in f32
    #pragma unroll
    for (int p = 0; p < 4; ++p){
        int zr = p*4 + rw;               // 0..15
        int iz = i0 + zr;
        int pix = (bt << 16) + (iz << 8) + jc;
        int base = (zr + 1)*YSW + 4 + jc;

        float vc[6], vn[6], vs[6];
        {
            float4 c4 = *(const float4*)&ys[base];
            vc[1]=c4.x; vc[2]=c4.y; vc[3]=c4.z; vc[4]=c4.w;
            vc[0]=ys[base-1]; vc[5]=ys[base+4];
            float4 n4 = *(const float4*)&ys[base+YSW];
            vn[1]=n4.x; vn[2]=n4.y; vn[3]=n4.z; vn[4]=n4.w;
            vn[0]=ys[base+YSW-1]; vn[5]=ys[base+YSW+4];
            float4 s4 = *(const float4*)&ys[base-YSW];
            vs[1]=s4.x; vs[2]=s4.y; vs[3]=s4.z; vs[4]=s4.w;
            vs[0]=ys[base-YSW-1]; vs[5]=ys[base-YSW+4];
        }
        float k2[4], m1[4], m2[4], hx[4], hs[4], hy[4], tv[4], z[4];
        ldf4(&fld[0*F_ELEMS + pix], k2);
        ldf4(&fld[1*F_ELEMS + pix], m1);
        ldf4(&fld[2*F_ELEMS + pix], m2);
        ldf4(&fld[3*F_ELEMS + pix], hx);
        ldf4(&fld[4*F_ELEMS + pix], hs);
        ldf4(&fld[5*F_ELEMS + pix], hy);
        ldf4(&fld[6*F_ELEMS + pix], tv);     // tau
        stencil4(k2, m1, m2, hx, hs, hy, vc, vn, vs, z);

        float4 xc = *(const float4*)&x[pix];
        float4 xp = make_float4(0,0,0,0);
        if (t > 0) xp = *(const float4*)&x[pix - IMG];
        const float* xcp = (const float*)&xc;
        const float* xpp = (const float*)&xp;
        #pragma unroll
        for (int q = 0; q < 4; ++q){
            float r = xcp[q] + z[q] - xpp[q];
            float dq = 1.0f/(tv[q]*tv[q]);   // D = 1/tau^2 in f32
            local += dq*r*r;
        }
        lprod *= tv[0]*tv[1];
        lprod *= tv[2]*tv[3];
    }

    // ---- reduction: wave shfl butterfly, then 4 partials ----
    float a = local;
    float b = __logf(lprod);             // sum(log tau) via single log of product
    #pragma unroll
    for (int off = 32; off > 0; off >>= 1){
        a += __shfl_down(a, off);
        b += __shfl_down(b, off);
    }
    if (cg == 0){ redA[rw] = a; redB[rw] = b; }
    __syncthreads();
    if (tid == 0){
        float ra = redA[0] + redA[1] + redA[2] + redA[3];
        float rb = redB[0] + redB[1] + redB[2] + redB[3];
        atomicAdd(out, 0.5f*ra + rb);    // 0.5*xQx - 0.5*logdetD
    }
}

// ---------------------------------------------------------------------------
// Cooperative mega-kernel: phase A (conv) -> grid sync -> phase B (A(A(x))).
// 512 blocks x 256 threads; 2 blocks/CU co-resident (LDS 48KB, VGPR small).
// ---------------------------------------------------------------------------
__global__ __launch_bounds__(256) void mega(
    const float* __restrict__ x, const float* __restrict__ w,
    _Float16* __restrict__ fld, float* __restrict__ out)
{
    __shared__ _Float16 xt[4*258*8];
    __shared__ _Float16 Wl[12*64*8];
    __shared__ float ys[18*YSW];
    __shared__ float redA[4], redB[4];

    const int bid = blockIdx.x;

    // Phase A: conv. bid -> (strip 0..127, b 0..3)
    conv_body(x, w, fld, out, bid & 127, bid >> 7, bid == 0, xt, Wl);

    __threadfence();                     // device-scope release of fld stores
    cg::this_grid().sync();              // all conv done, fld visible

    // Phase B: fused A(A(x)). bid -> (istrip 0..15, bt 0..31)
    fused_body(x, fld, out, bid & 15, bid >> 4, ys, redA, redB);
}

// Fallback kernels (used only if cooperative launch is unavailable).
__global__ __launch_bounds__(256) void conv_mfma(
    const float* __restrict__ x, const float* __restrict__ w,
    _Float16* __restrict__ fld, float* __restrict__ out)
{
    __shared__ _Float16 xt[4*258*8];
    __shared__ _Float16 Wl[12*64*8];
    conv_body(x, w, fld, out, blockIdx.x, blockIdx.y,
              (blockIdx.x == 0 && blockIdx.y == 0), xt, Wl);
}

__global__ __launch_bounds__(256) void fused_A(
    const float* __restrict__ x, const _Float16* __restrict__ fld,
    float* __restrict__ out)
{
    __shared__ float ys[18*YSW];
    __shared__ float redA[4], redB[4];
    fused_body(x, fld, out, blockIdx.x, blockIdx.y, ys, redA, redB);
}

extern "C" void kernel_launch(void* const* d_in, const int* in_sizes, int n_in,
                              void* d_out, int out_size, void* d_ws, size_t ws_size,
                              hipStream_t stream)
{
    const float* x = (const float*)d_in[0];
    const float* w = (const float*)d_in[1];
    float* out = (float*)d_out;
    _Float16* fld = (_Float16*)d_ws;

    void* args[] = { (void*)&x, (void*)&w, (void*)&fld, (void*)&out };
    hipError_t err = hipLaunchCooperativeKernel(
        (const void*)mega, dim3(512), dim3(256), args, 0, stream);
    if (err != hipSuccess){
        // Fallback: two plain launches (identical math).
        conv_mfma<<<dim3(128, 4), 256, 0, stream>>>(x, w, fld, out);
        fused_A<<<dim3(16, 32), 256, 0, stream>>>(x, fld, out);
    }
}

// Round 4
// 98.821 us; speedup vs baseline: 2.4181x; 2.4181x over previous
//
#include <hip/hip_runtime.h>

#define F_ELEMS 2097152            // B*T*H*W = 4*8*256*256 (elements per field)
#define IMG 65536                  // H*W

typedef _Float16 half8  __attribute__((ext_vector_type(8)));
typedef _Float16 half2v __attribute__((ext_vector_type(2)));
typedef _Float16 half4v __attribute__((ext_vector_type(4)));
typedef float    floatx4 __attribute__((ext_vector_type(4)));

__device__ __forceinline__ float sigm(float x){ return 1.0f/(1.0f + __expf(-x)); }
__device__ __forceinline__ float tanh_fast(float x){
    float t = __expf(2.0f*x);
    return 1.0f - 2.0f/(t + 1.0f);
}

// ---------------------------------------------------------------------------
// K1: conv 3x3 (8ch -> 64ch) via MFMA f16 implicit GEMM, fused pointwise.
// 1-D grid of 512 blocks, XCD-co-located with K2's consumers:
//   bid%8 == band (strip>>3) %8  ==  K2's (istrip + 16*bt)%8.
// Per-XCD fld share = 29.4/8 = 3.7 MB < 4 MB L2, so K2's fld reads hit the
// producing XCD's L2 instead of HBM. (XCD round-robin on linear block id is
// a locality heuristic only — correctness is mapping-independent.)
// Fields stored f16: 0 kappa^2, 1 m1, 2 m2, 3 Hxx, 4 Hs, 5 Hyy, 6 tau.
// ---------------------------------------------------------------------------
__global__ __launch_bounds__(256) void conv_mfma(
    const float* __restrict__ x, const float* __restrict__ w,
    _Float16* __restrict__ fld, float* __restrict__ out)
{
    __shared__ _Float16 xt[4*258*8];     // 4 rows, 258 cols (halo), 8 ch
    __shared__ _Float16 Wl[12*64*8];     // [tap][oc][c]

    const int tid = threadIdx.x;

    // decode: xcd = bid&7 (= band%8), q = bid>>3: sub=q&7, hi=(q>>3)&1, b=q>>4
    // strip = (hi*8 + xcd)*8 + sub  -> bijective onto 0..127 per b.
    const int bid = blockIdx.x;
    const int xcd = bid & 7;
    const int q   = bid >> 3;
    const int sub = q & 7;
    const int hi  = (q >> 3) & 1;
    const int b   = q >> 4;
    const int strip = ((hi << 3) + xcd)*8 + sub;
    const int i0  = strip << 1;          // strip of 2 rows

    // K2 runs after K1 in stream order, so this zero is safe (no atomics here).
    if (tid == 0 && bid == 0) out[0] = 0.0f;

    // ---- stage x (f32 -> f16, channel pairs for 4B LDS writes) ----
    for (int e = tid; e < 258*4*4; e += 256){
        int cc = e % 258;
        int rr = (e/258) & 3;
        int cp = e / (258*4);            // channel pair 0..3
        int gi = i0 - 1 + rr, gj = cc - 1;
        float v0 = 0.0f, v1 = 0.0f;
        if (gi >= 0 && gi < 256 && gj >= 0 && gj < 256){
            int base = ((b*8 + 2*cp) << 16) + (gi << 8) + gj;
            v0 = x[base];
            v1 = x[base + IMG];
        }
        half2v h; h[0] = (_Float16)v0; h[1] = (_Float16)v1;
        *(half2v*)&xt[(rr*258 + cc)*8 + 2*cp] = h;
    }
    // ---- stage weights [tap][oc][c], zero-pad taps 9..11 ----
    for (int e = tid; e < 12*64*8; e += 256){
        int c  = e & 7;
        int oc = (e >> 3) & 63;
        int t  = e >> 9;
        float v = (t < 9) ? w[(oc*8 + c)*9 + t] : 0.0f;
        Wl[e] = (_Float16)v;             // e == (t*64+oc)*8 + c
    }
    __syncthreads();

    const int lane = tid & 63;
    const int quad = lane >> 4;
    const int l16  = lane & 15;
    const int wv   = tid >> 6;

    // Weight frags (B operand): B[k=quad*8+j][n=oc=ot*16+l16]
    half8 afr[4][3];
    int boff[3];
    #pragma unroll
    for (int s = 0; s < 3; ++s){
        int t  = s*4 + quad;
        afr[0][s] = *(const half8*)&Wl[(t*64 +  0 + l16)*8];
        afr[1][s] = *(const half8*)&Wl[(t*64 + 16 + l16)*8];
        afr[2][s] = *(const half8*)&Wl[(t*64 + 32 + l16)*8];
        afr[3][s] = *(const half8*)&Wl[(t*64 + 48 + l16)*8];
        int tc = (t < 9) ? t : 8;        // taps >=9 have zero weights
        int dh = tc / 3, dw = tc - dh*3;
        boff[s] = (dh*258 + dw)*8;
    }

    // it-invariant epilogue constants: lane (quad,l16) holds px = base+quad*4+rg
    // of oc = ot*16 + l16.
    const bool lo  = (l16 < 8);
    const int  tlo = l16 << 16, thi = (l16 - 8) << 16;
    const int  off0 = lo ? (0*F_ELEMS + tlo) : (1*F_ELEMS + thi);  // kappa^2 / m1
    const int  off1 = lo ? (2*F_ELEMS + tlo) : (3*F_ELEMS + thi);  // m2 / Hxx
    const int  off2 = 4*F_ELEMS + tlo;                             // Hs (lo only)
    const int  off3 = lo ? (5*F_ELEMS + tlo) : (6*F_ELEMS + thi);  // Hyy / tau

    // 32 groups of 16 px (2 rows x 16 col-groups); 8 iters per wave
    #pragma unroll 2
    for (int it = 0; it < 8; ++it){
        const int g   = it*4 + wv;
        const int r   = g >> 4;
        const int jb  = ((g & 15) << 4) + l16;   // A-frag row = px = l16
        const int xoff = (r*258 + jb)*8;

        floatx4 acc0 = {0,0,0,0}, acc1 = {0,0,0,0}, acc2 = {0,0,0,0}, acc3 = {0,0,0,0};
        #pragma unroll
        for (int s = 0; s < 3; ++s){
            half8 bf = *(const half8*)&xt[xoff + boff[s]];
            acc0 = __builtin_amdgcn_mfma_f32_16x16x32_f16(bf, afr[0][s], acc0, 0, 0, 0);
            acc1 = __builtin_amdgcn_mfma_f32_16x16x32_f16(bf, afr[1][s], acc1, 0, 0, 0);
            acc2 = __builtin_amdgcn_mfma_f32_16x16x32_f16(bf, afr[2][s], acc2, 0, 0, 0);
            acc3 = __builtin_amdgcn_mfma_f32_16x16x32_f16(bf, afr[3][s], acc3, 0, 0, 0);
        }

        // epilogue: lane holds px = jb0 + quad*4 + rg (rg=0..3) of oc = ot*16+l16
        const int jb0  = (g & 15) << 4;
        const int pixb = (b << 19) + ((i0 + r) << 8) + jb0 + (quad << 2);

        half4v h0, h1, h2, h3;
        #pragma unroll
        for (int rg = 0; rg < 4; ++rg){
            // ot=0: oc=l16: kappa (l16<8) / m1 (l16>=8)
            float v0 = acc0[rg];
            float s0 = 0.99f*sigm(v0) + 0.01f;
            h0[rg] = (_Float16)(lo ? s0*s0 : v0);
            // ot=1: m2 (l16<8) / Hxx (l16>=8)
            float v1 = acc1[rg];
            h1[rg] = (_Float16)(lo ? v1 : 0.99f*sigm(v1) + 0.01f);
            // ot=2: Hxy (l16<8) + Hyx (l16>=8) -> Hs on lo lanes
            float th  = 0.1f*tanh_fast(acc2[rg]);
            float oth = __shfl_xor(th, 8, 64);
            h2[rg] = (_Float16)(th + oth);
            // ot=3: Hyy (l16<8) / tau (l16>=8)
            float sg = sigm(acc3[rg]);
            h3[rg] = (_Float16)(lo ? 0.99f*sg + 0.01f : 9.9f*sg + 0.1f);
        }
        *(half4v*)&fld[off0 + pixb] = h0;
        *(half4v*)&fld[off1 + pixb] = h1;
        if (lo) *(half4v*)&fld[off2 + pixb] = h2;
        *(half4v*)&fld[off3 + pixb] = h3;
    }
}

// ---------------------------------------------------------------------------
// A(u) with f16 coefficient fields.
// ---------------------------------------------------------------------------
__device__ __forceinline__ void ldf4(const _Float16* __restrict__ p, float o[4]){
    half4v h = *(const half4v*)p;
    o[0] = (float)h[0]; o[1] = (float)h[1]; o[2] = (float)h[2]; o[3] = (float)h[3];
}

__device__ __forceinline__ void row6(const float* __restrict__ u, int rb, int j0, float v[6]){
    const float4 c4 = *(const float4*)&u[rb + j0];
    v[1] = c4.x; v[2] = c4.y; v[3] = c4.z; v[4] = c4.w;
    v[0] = (j0 > 0)   ? u[rb + j0 - 1] : 0.0f;
    v[5] = (j0 < 252) ? u[rb + j0 + 4] : 0.0f;
}

__device__ __forceinline__ void stencil4(const float k2[4], const float m1[4],
    const float m2[4], const float hx[4], const float hs[4], const float hy[4],
    const float vc[6], const float vn[6], const float vs[6], float rp[4])
{
    #pragma unroll
    for (int p = 0; p < 4; ++p){
        float hxx = hx[p], hyy = hy[p];
        rp[p] = (k2[p] + 2.0f*(hxx + hyy))*vc[p+1]
              + (0.5f*m1[p] - hxx)*vc[p+2]
              - (0.5f*m1[p] + hxx)*vc[p]
              + (0.5f*m2[p] - hyy)*vn[p+1]
              - (0.5f*m2[p] + hyy)*vs[p+1]
              - 0.25f*hs[p]*(vn[p+2] - vs[p+2] - vn[p] + vs[p]);
    }
}

// ---------------------------------------------------------------------------
// K2: fused z = A(A(x)); r = x + z - x_prev;
// out += 0.5*sum(D r^2) + sum(log tau)   (== 0.5*(xQx - logdetD))
// Block: 16-row strip x 256 cols of one (b,t) image. y kept in LDS (18 rows
// incl. halo, recomputed per strip). Natural grid mapping: linear id
// istrip + 16*bt -> XCD = istrip%8, matching conv's producers.
// ---------------------------------------------------------------------------
#define YSW 268
__global__ __launch_bounds__(256) void fused_A(
    const float* __restrict__ x, const _Float16* __restrict__ fld,
    float* __restrict__ out)
{
    __shared__ float ys[18*YSW];
    __shared__ float redA[4], redB[4];

    const int tid = threadIdx.x;
    const int cg  = tid & 63;            // col group (4 cols)
    const int rw  = tid >> 6;            // row within pass
    const int jc  = cg << 2;
    const int bt  = blockIdx.y;          // 0..31
    const int t   = bt & 7;
    const int i0  = blockIdx.x << 4;

    // zero halo columns (j=-1 -> idx 3, j=256 -> idx 260)
    if (tid < 18){ ys[tid*YSW + 3] = 0.0f; ys[tid*YSW + 260] = 0.0f; }

    // ---- phase 1: y = A(x) on rows i0-1 .. i0+16 ----
    for (int p = 0; p < 5; ++p){
        int yr = p*4 + rw;               // wave-uniform branch
        if (yr < 18){
            int iy = i0 - 1 + yr;
            float y[4] = {0,0,0,0};
            if (iy >= 0 && iy < 256){
                int pix = (bt << 16) + (iy << 8) + jc;
                int rb  = pix - jc;
                float vc[6], vn[6], vs[6];
                row6(x, rb, jc, vc);
                if (iy < 255) row6(x, rb + 256, jc, vn);
                else { vn[0]=vn[1]=vn[2]=vn[3]=vn[4]=vn[5]=0.0f; }
                if (iy > 0) row6(x, rb - 256, jc, vs);
                else { vs[0]=vs[1]=vs[2]=vs[3]=vs[4]=vs[5]=0.0f; }
                float k2[4], m1[4], m2[4], hx[4], hs[4], hy[4];
                ldf4(&fld[0*F_ELEMS + pix], k2);
                ldf4(&fld[1*F_ELEMS + pix], m1);
                ldf4(&fld[2*F_ELEMS + pix], m2);
                ldf4(&fld[3*F_ELEMS + pix], hx);
                ldf4(&fld[4*F_ELEMS + pix], hs);
                ldf4(&fld[5*F_ELEMS + pix], hy);
                stencil4(k2, m1, m2, hx, hs, hy, vc, vn, vs, y);
            }
            float4 y4 = make_float4(y[0], y[1], y[2], y[3]);
            *(float4*)&ys[yr*YSW + 4 + jc] = y4;
        }
    }
    __syncthreads();

    // ---- phase 2: z = A(y); accumulate D*r^2 and prod(tau) ----
    float local = 0.0f;
    float lprod = 1.0f;                  // product of 16 taus, range safe in f32
    #pragma unroll
    for (int p = 0; p < 4; ++p){
        int zr = p*4 + rw;               // 0..15
        int iz = i0 + zr;
        int pix = (bt << 16) + (iz << 8) + jc;
        int base = (zr + 1)*YSW + 4 + jc;

        float vc[6], vn[6], vs[6];
        {
            float4 c4 = *(const float4*)&ys[base];
            vc[1]=c4.x; vc[2]=c4.y; vc[3]=c4.z; vc[4]=c4.w;
            vc[0]=ys[base-1]; vc[5]=ys[base+4];
            float4 n4 = *(const float4*)&ys[base+YSW];
            vn[1]=n4.x; vn[2]=n4.y; vn[3]=n4.z; vn[4]=n4.w;
            vn[0]=ys[base+YSW-1]; vn[5]=ys[base+YSW+4];
            float4 s4 = *(const float4*)&ys[base-YSW];
            vs[1]=s4.x; vs[2]=s4.y; vs[3]=s4.z; vs[4]=s4.w;
            vs[0]=ys[base-YSW-1]; vs[5]=ys[base-YSW+4];
        }
        float k2[4], m1[4], m2[4], hx[4], hs[4], hy[4], tv[4], z[4];
        ldf4(&fld[0*F_ELEMS + pix], k2);
        ldf4(&fld[1*F_ELEMS + pix], m1);
        ldf4(&fld[2*F_ELEMS + pix], m2);
        ldf4(&fld[3*F_ELEMS + pix], hx);
        ldf4(&fld[4*F_ELEMS + pix], hs);
        ldf4(&fld[5*F_ELEMS + pix], hy);
        ldf4(&fld[6*F_ELEMS + pix], tv);     // tau
        stencil4(k2, m1, m2, hx, hs, hy, vc, vn, vs, z);

        float4 xc = *(const float4*)&x[pix];
        float4 xp = make_float4(0,0,0,0);
        if (t > 0) xp = *(const float4*)&x[pix - IMG];
        const float* xcp = (const float*)&xc;
        const float* xpp = (const float*)&xp;
        #pragma unroll
        for (int q = 0; q < 4; ++q){
            float r = xcp[q] + z[q] - xpp[q];
            float dq = 1.0f/(tv[q]*tv[q]);   // D = 1/tau^2 in f32
            local += dq*r*r;
        }
        lprod *= tv[0]*tv[1];
        lprod *= tv[2]*tv[3];
    }

    // ---- reduction: wave shfl butterfly, then 4 partials ----
    float a = local;
    float b = __logf(lprod);             // sum(log tau) via single log of product
    #pragma unroll
    for (int off = 32; off > 0; off >>= 1){
        a += __shfl_down(a, off);
        b += __shfl_down(b, off);
    }
    if (cg == 0){ redA[rw] = a; redB[rw] = b; }
    __syncthreads();
    if (tid == 0){
        float ra = redA[0] + redA[1] + redA[2] + redA[3];
        float rb = redB[0] + redB[1] + redB[2] + redB[3];
        atomicAdd(out, 0.5f*ra + rb);    // 0.5*xQx - 0.5*logdetD
    }
}

extern "C" void kernel_launch(void* const* d_in, const int* in_sizes, int n_in,
                              void* d_out, int out_size, void* d_ws, size_t ws_size,
                              hipStream_t stream)
{
    const float* x = (const float*)d_in[0];
    const float* w = (const float*)d_in[1];
    float* out = (float*)d_out;
    _Float16* fld = (_Float16*)d_ws;

    conv_mfma<<<dim3(512), 256, 0, stream>>>(x, w, fld, out);
    fused_A<<<dim3(16, 32), 256, 0, stream>>>(x, fld, out);
}